// Round 1
// baseline (160.866 us; speedup 1.0000x reference)
//
#include <hip/hip_runtime.h>

// Problem constants (from reference): x (4, 32, 256, 256) fp32,
// WINDOW=16, STRIDE=8, PADDING=0, EPS=1e-6
// out[b, l, c, ph, pw] = x[b, c, ho*8+ph, wo*8+pw] + EPS * sum(16x16 patch)
// with l = ho*31 + wo, out shape (4, 961, 32, 16, 16).

#define BB   4
#define CC   32
#define HH   256
#define WW   256
#define WIN  16
#define STR  8
#define HO   31
#define WO   31
#define LL   (HO * WO)   // 961
#define EPSF 1e-6f

// One wave (64 lanes) handles one (b, l, c) patch:
//  - lane i loads float4 at row (i>>2), col-quad (i&3) of the 16x16 patch
//  - wave-wide shfl_xor reduction for the patch sum
//  - lane i stores float4 at output offset patch_base + i*4 (fully coalesced:
//    256 contiguous floats per patch = 1 KB per wave store)
__global__ __launch_bounds__(256) void
extract_patches_kernel(const float* __restrict__ x, float* __restrict__ out) {
    const int lane = threadIdx.x & 63;
    const int wave = threadIdx.x >> 6;

    // grid: x = 8 (channel quads), y = L (961), z = B (4)
    const int c  = (blockIdx.x << 2) + wave;   // 4 waves/block -> 4 channels
    const int l  = blockIdx.y;
    const int b  = blockIdx.z;
    const int ho = l / WO;            // small constant divide, compiler magic-muls
    const int wo = l - ho * WO;

    const int r  = lane >> 2;         // patch row 0..15
    const int cq = lane & 3;          // col quad 0..3

    // input address: 16B-aligned (offset is a multiple of 4 floats)
    const size_t in_off =
        (((size_t)(b * CC + c) * HH + (size_t)(ho * STR + r)) * WW) +
        (size_t)(wo * STR + cq * 4);
    const float4 v = *(const float4*)(x + in_off);

    // patch sum: per-lane partial then 64-lane butterfly
    float s = v.x + v.y + v.z + v.w;
#pragma unroll
    for (int off = 32; off; off >>= 1) s += __shfl_xor(s, off, 64);

    const float e = EPSF * s;
    const float4 o = make_float4(v.x + e, v.y + e, v.z + e, v.w + e);

    // output: (((b*L + l)*C + c) * 256) + lane*4
    const size_t out_off =
        ((size_t)((b * LL + l) * CC + c) << 8) + (size_t)(lane << 2);
    *(float4*)(out + out_off) = o;
}

extern "C" void kernel_launch(void* const* d_in, const int* in_sizes, int n_in,
                              void* d_out, int out_size, void* d_ws, size_t ws_size,
                              hipStream_t stream) {
    const float* x = (const float*)d_in[0];
    float* out = (float*)d_out;

    dim3 grid(CC / 4, LL, BB);   // (8, 961, 4) blocks, 4 waves each
    dim3 block(256);
    extract_patches_kernel<<<grid, block, 0, stream>>>(x, out);
}

// Round 2
// 148.567 us; speedup vs baseline: 1.0828x; 1.0828x over previous
//
#include <hip/hip_runtime.h>

// x: (4, 32, 256, 256) fp32. WINDOW=16, STRIDE=8, EPS=1e-6.
// out[b, l, c, ph, pw] = x[b, c, ho*8+ph, wo*8+pw] + EPS * sum(16x16 patch),
// l = ho*31 + wo, out shape (4, 961, 32, 16, 16).
//
// Strategy: one block (256 thr, 4 waves) per (b, c, ho) row-strip.
//  - Stage the 16-row x-strip (16 KB, contiguous) into LDS via float4.
//  - While staging, fold 8-wide chunk sums (shfl_xor(1) pairs a chunk).
//  - psum[wo] = sum of 32 chunk sums (cols [8wo, 8wo+16) over 16 rows).
//  - Emit 31 patches; each patch = one wave's fully-coalesced 1 KB store.

#define BB   4
#define CC   32
#define HH   256
#define WW   256
#define STR  8
#define HOC  31
#define WOC  31
#define LL   (HOC * WOC)   // 961
#define EPSF 1e-6f
#define PITCH 272          // 256 + 16 floats: rows alternate bank halves

__global__ __launch_bounds__(256) void
extract_patches_strip(const float* __restrict__ x, float* __restrict__ out) {
    __shared__ float strip[16 * PITCH];   // 17408 B
    __shared__ float cs[16 * 32];         // chunk sums: [row][chunk0..31], 2 KB
    __shared__ float epsP[32];            // eps * patch sum per wo (31 used)

    const int tid = threadIdx.x;
    const int c   = blockIdx.x;   // 0..31
    const int ho  = blockIdx.y;   // 0..30
    const int b   = blockIdx.z;   // 0..3

    const float* src = x + ((size_t)(b * CC + c) * HH + (size_t)(ho * STR)) * WW;

    // ---- stage 16 KB strip + chunk sums ----
#pragma unroll
    for (int it = 0; it < 4; ++it) {
        const int g   = (it * 256 + tid) * 4;   // float index in strip, 0..4095
        const float4 v = *(const float4*)(src + g);
        const int row = g >> 8;                 // /256
        const int col = g & 255;
        *(float4*)(&strip[row * PITCH + col]) = v;
        float s4 = v.x + v.y + v.z + v.w;
        s4 += __shfl_xor(s4, 1, 64);            // pair (t, t^1) = one 8-chunk
        if ((tid & 1) == 0)
            cs[g >> 3] = s4;                    // chunk idx 0..511 = row*32+k
    }
    __syncthreads();

    // ---- patch sums: thread wo sums rows 0..15 x chunks {2wo, 2wo+1} ----
    if (tid < WOC) {
        float s = 0.f;
#pragma unroll
        for (int r = 0; r < 16; ++r)
            s += cs[r * 32 + 2 * tid] + cs[r * 32 + 2 * tid + 1];
        epsP[tid] = EPSF * s;
    }
    __syncthreads();

    // ---- emit 31 patches: wave w handles wo = 4p + w ----
    const int wave  = tid >> 6;
    const int lane  = tid & 63;
    const int prow  = lane >> 2;        // patch row 0..15
    const int pcol4 = (lane & 3) * 4;   // patch col quad
    float* dstbase = out
        + (((size_t)b * LL + (size_t)ho * WOC) * CC + c) * 256
        + (size_t)(lane * 4);
#pragma unroll
    for (int p = 0; p < 8; ++p) {
        const int wo = p * 4 + wave;
        if (wo < WOC) {
            const float4 v =
                *(const float4*)(&strip[prow * PITCH + wo * STR + pcol4]);
            const float e = epsP[wo];
            const float4 o = make_float4(v.x + e, v.y + e, v.z + e, v.w + e);
            // patch stride in out = C*256 floats = 8192
            *(float4*)(dstbase + ((size_t)wo << 13)) = o;
        }
    }
}

extern "C" void kernel_launch(void* const* d_in, const int* in_sizes, int n_in,
                              void* d_out, int out_size, void* d_ws, size_t ws_size,
                              hipStream_t stream) {
    const float* x = (const float*)d_in[0];
    float* out = (float*)d_out;

    dim3 grid(CC, HOC, BB);   // (32, 31, 4) = 3968 blocks
    dim3 block(256);
    extract_patches_strip<<<grid, block, 0, stream>>>(x, out);
}